// Round 1
// baseline (1042.847 us; speedup 1.0000x reference)
//
#include <hip/hip_runtime.h>
#include <cstdint>
#include <cstddef>

// Problem constants (from reference): N=50000, E=600000, D=128, C=40, M=25000
#define DIM 128

// ---------------------------------------------------------------------------
// CSR build: count in-degrees, prefix-scan, fill column lists
// ---------------------------------------------------------------------------
__global__ void k_count(const int* __restrict__ dst, int* __restrict__ count, int e) {
    int i = blockIdx.x * 256 + threadIdx.x;
    if (i < e) atomicAdd(&count[dst[i]], 1);
}

__global__ void k_dinv(const int* __restrict__ count, float* __restrict__ dinv, int n) {
    int i = blockIdx.x * 256 + threadIdx.x;
    if (i < n) dinv[i] = rsqrtf(1.0f + (float)count[i]);   // deg includes self-loop
}

// Single-block scan: 1024 threads = 16 waves; shuffle scan per wave + LDS wave sums.
__global__ __launch_bounds__(1024)
void k_scan(const int* __restrict__ count, int* __restrict__ row_ptr,
            int* __restrict__ cursor, int n) {
    __shared__ int wsum[16];
    __shared__ int s_carry;
    int tid = threadIdx.x;
    int lane = tid & 63, wid = tid >> 6;
    if (tid == 0) s_carry = 0;
    __syncthreads();
    for (int base = 0; base < n; base += 1024) {
        int i = base + tid;
        int v = (i < n) ? count[i] : 0;
        int x = v;
        #pragma unroll
        for (int off = 1; off < 64; off <<= 1) {
            int y = __shfl_up(x, off, 64);
            if (lane >= off) x += y;
        }
        if (lane == 63) wsum[wid] = x;
        __syncthreads();
        int waveoff = 0, total = 0;
        #pragma unroll
        for (int w = 0; w < 16; ++w) {
            int s = wsum[w];
            if (w < wid) waveoff += s;
            total += s;
        }
        int carry = s_carry;
        int inc = x + waveoff + carry;       // inclusive prefix of count[0..i]
        if (i < n) { row_ptr[i + 1] = inc; cursor[i] = inc - v; }
        __syncthreads();
        if (tid == 0) s_carry = carry + total;
        __syncthreads();
    }
    if (tid == 0) row_ptr[0] = 0;
}

__global__ void k_fill(const int* __restrict__ src, const int* __restrict__ dst,
                       int* __restrict__ cursor, int* __restrict__ col, int e) {
    int i = blockIdx.x * 256 + threadIdx.x;
    if (i < e) {
        int d = dst[i];
        int pos = atomicAdd(&cursor[d], 1);
        col[pos] = src[i];
    }
}

// ---------------------------------------------------------------------------
// Matmul: out[N,128] = (relu?)in[N,128] @ W[128,128], fp32.
// Block = 128 threads (2 waves). Each thread owns one output column (W column
// slice in 128 VGPRs); 32 input rows staged in LDS, read via same-address
// ds_read_b128 broadcast. FMA-throughput-bound by construction.
// ---------------------------------------------------------------------------
__global__ __launch_bounds__(128, 2)
void k_matmul(const float* __restrict__ in, const float* __restrict__ Wg,
              float* __restrict__ outp, int n, int relu_in) {
    __shared__ float lds[32 * 128];
    int tid = threadIdx.x;
    int r0 = blockIdx.x * 32;

    // Stage 32 rows (guarded) as float4, optional relu on load.
    const float4* gin = (const float4*)(in + (size_t)r0 * DIM);
    float4* l4 = (float4*)lds;
    #pragma unroll
    for (int it = 0; it < 8; ++it) {
        int idx = it * 128 + tid;          // float4 index, 1024 total = 32 rows
        int row = idx >> 5;
        float4 v;
        if (r0 + row < n) v = gin[idx];
        else { v.x = 0.f; v.y = 0.f; v.z = 0.f; v.w = 0.f; }
        if (relu_in) {
            v.x = fmaxf(v.x, 0.f); v.y = fmaxf(v.y, 0.f);
            v.z = fmaxf(v.z, 0.f); v.w = fmaxf(v.w, 0.f);
        }
        l4[idx] = v;
    }
    __syncthreads();

    int col = tid;                          // 0..127 across 2 waves
    float w[DIM];
    #pragma unroll
    for (int k = 0; k < DIM; ++k) w[k] = Wg[k * DIM + col];   // coalesced (64 lanes contiguous)

    for (int r = 0; r < 32; ++r) {
        if (r0 + r >= n) break;
        const float4* arow = (const float4*)(lds + r * DIM);
        float a0 = 0.f, a1 = 0.f, a2 = 0.f, a3 = 0.f;
        #pragma unroll
        for (int kq = 0; kq < 32; ++kq) {
            float4 a = arow[kq];            // broadcast ds_read_b128
            a0 = fmaf(a.x, w[4 * kq + 0], a0);
            a1 = fmaf(a.y, w[4 * kq + 1], a1);
            a2 = fmaf(a.z, w[4 * kq + 2], a2);
            a3 = fmaf(a.w, w[4 * kq + 3], a3);
        }
        outp[(size_t)(r0 + r) * DIM + col] = (a0 + a1) + (a2 + a3);
    }
}

// ---------------------------------------------------------------------------
// Propagation: out[d] = sum_{e: dst=d} dinv[src]*dinv[d]*h[src] + dinv[d]^2*h[d]
//              + bscale*bias.  One wave per dst node, 2 floats per lane.
// Optionally accum[d] += relu(out[d])  (fused for the cell3 input sum).
// ---------------------------------------------------------------------------
__global__ __launch_bounds__(256)
void k_prop(const float* __restrict__ h, const int* __restrict__ row_ptr,
            const int* __restrict__ col, const float* __restrict__ dinv,
            const float* __restrict__ bias, float bscale,
            float* __restrict__ outp, float* __restrict__ accum, int n) {
    int wid  = (blockIdx.x * 256 + threadIdx.x) >> 6;
    int lane = threadIdx.x & 63;
    if (wid >= n) return;
    int beg = row_ptr[wid], end = row_ptr[wid + 1];
    float di = dinv[wid];
    const float2* h2 = (const float2*)h;
    float ax = 0.f, ay = 0.f;
    int j = beg;
    int s_next = (j < end) ? col[j] : 0;
    for (; j < end; ) {
        int s = s_next;
        ++j;
        s_next = (j < end) ? col[j] : 0;   // prefetch next column index
        float wgt = dinv[s] * di;
        float2 v = h2[(size_t)s * 64 + lane];
        ax = fmaf(wgt, v.x, ax);
        ay = fmaf(wgt, v.y, ay);
    }
    float2 sv = h2[(size_t)wid * 64 + lane];
    float w2 = di * di;
    ax = fmaf(w2, sv.x, ax);
    ay = fmaf(w2, sv.y, ay);
    float2 b = ((const float2*)bias)[lane];
    ax += bscale * b.x;
    ay += bscale * b.y;
    float2 o; o.x = ax; o.y = ay;
    ((float2*)outp)[(size_t)wid * 64 + lane] = o;
    if (accum) {
        float2* a2 = (float2*)accum + (size_t)wid * 64 + lane;
        float2 av = *a2;
        av.x += fmaxf(ax, 0.f);
        av.y += fmaxf(ay, 0.f);
        *a2 = av;
    }
}

// A = relu(c0) + relu(c1), elementwise float4
__global__ void k_addrelu2(const float4* __restrict__ a, const float4* __restrict__ b,
                           float4* __restrict__ o, int n4) {
    int i = blockIdx.x * 256 + threadIdx.x;
    if (i < n4) {
        float4 x = a[i], y = b[i], r;
        r.x = fmaxf(x.x, 0.f) + fmaxf(y.x, 0.f);
        r.y = fmaxf(x.y, 0.f) + fmaxf(y.y, 0.f);
        r.z = fmaxf(x.z, 0.f) + fmaxf(y.z, 0.f);
        r.w = fmaxf(x.w, 0.f) + fmaxf(y.w, 0.f);
        o[i] = r;
    }
}

// column sums of Wh [128,40]
__global__ void k_whsum(const float* __restrict__ Wh, float* __restrict__ whs, int C) {
    int c = threadIdx.x;
    if (c < C) {
        float s = 0.f;
        for (int d = 0; d < DIM; ++d) s += Wh[d * C + c];
        whs[c] = s;
    }
}

// pred[m,c] = sum_d v_d Wh[d,c] - L*whsum[c] + bh[c],  L = max + log(sum exp(v-max))
// One wave per label row.
__global__ __launch_bounds__(256)
void k_final(const float* __restrict__ C3, const int* __restrict__ labels,
             const float* __restrict__ Wh, const float* __restrict__ whs,
             const float* __restrict__ bh, float* __restrict__ outp,
             int m_total, int C) {
    __shared__ float vl[4][DIM];
    int wid = threadIdx.x >> 6, lane = threadIdx.x & 63;
    int m = blockIdx.x * 4 + wid;
    if (m >= m_total) return;
    int row = labels[m];
    float2 v = ((const float2*)(C3 + (size_t)row * DIM))[lane];
    float mx = fmaxf(v.x, v.y);
    #pragma unroll
    for (int off = 32; off > 0; off >>= 1) mx = fmaxf(mx, __shfl_xor(mx, off, 64));
    float s = expf(v.x - mx) + expf(v.y - mx);
    #pragma unroll
    for (int off = 32; off > 0; off >>= 1) s += __shfl_xor(s, off, 64);
    float L = mx + logf(s);
    vl[wid][2 * lane]     = v.x;
    vl[wid][2 * lane + 1] = v.y;
    // same-wave LDS RAW: compiler inserts the required lgkmcnt wait
    if (lane < C) {
        float acc = 0.f;
        #pragma unroll 8
        for (int d = 0; d < DIM; ++d)
            acc = fmaf(vl[wid][d], Wh[d * C + lane], acc);
        outp[(size_t)m * C + lane] = acc - L * whs[lane] + bh[lane];
    }
}

// ---------------------------------------------------------------------------
extern "C" void kernel_launch(void* const* d_in, const int* in_sizes, int n_in,
                              void* d_out, int out_size, void* d_ws, size_t ws_size,
                              hipStream_t stream) {
    const float* x      = (const float*)d_in[0];
    const int*   edges  = (const int*)d_in[1];
    const int*   labels = (const int*)d_in[2];
    const float* W0 = (const float*)d_in[3];
    const float* b0 = (const float*)d_in[4];
    const float* W1 = (const float*)d_in[5];
    const float* b1 = (const float*)d_in[6];
    const float* W2 = (const float*)d_in[7];
    const float* b2 = (const float*)d_in[8];
    const float* W3 = (const float*)d_in[9];
    const float* b3 = (const float*)d_in[10];
    const float* Wh = (const float*)d_in[11];
    const float* bh = (const float*)d_in[12];
    float* out = (float*)d_out;

    const int N = in_sizes[0] / DIM;       // 50000
    const int E = in_sizes[1] / 2;         // 600000
    const int M = in_sizes[2];             // 25000
    const int C = in_sizes[12];            // 40

    // Workspace layout (256B-aligned slices)
    char* ws = (char*)d_ws;
    auto alloc = [&](size_t bytes) {
        char* p = ws;
        ws += (bytes + 255) & ~(size_t)255;
        return p;
    };
    float* dinv    = (float*)alloc((size_t)N * 4);
    int*   count   = (int*)  alloc((size_t)N * 4);
    int*   row_ptr = (int*)  alloc((size_t)(N + 1) * 4);
    int*   cursor  = (int*)  alloc((size_t)N * 4);
    int*   col     = (int*)  alloc((size_t)E * 4);
    float* whs     = (float*)alloc(256);
    float* H   = (float*)alloc((size_t)N * DIM * 4);
    float* Cb0 = (float*)alloc((size_t)N * DIM * 4);   // holds cell0, later cell2
    float* Cb1 = (float*)alloc((size_t)N * DIM * 4);   // holds cell1, later cell3
    float* Ab  = (float*)alloc((size_t)N * DIM * 4);   // running relu-sum

    const int* src = edges;
    const int* dst = edges + E;

    int egrid = (E + 255) / 256;
    int ngrid = (N + 255) / 256;
    int mmgrid = (N + 31) / 32;
    int pgrid  = (N + 3) / 4;              // one wave per node, 4 waves/block

    // --- CSR build ---
    hipMemsetAsync(count, 0, (size_t)N * 4, stream);
    k_count<<<egrid, 256, 0, stream>>>(dst, count, E);
    k_dinv <<<ngrid, 256, 0, stream>>>(count, dinv, N);
    k_scan <<<1, 1024, 0, stream>>>(count, row_ptr, cursor, N);
    k_fill <<<egrid, 256, 0, stream>>>(src, dst, cursor, col, E);
    k_whsum<<<1, 64, 0, stream>>>(Wh, whs, C);

    // --- cell0 = Â(x W0) + b0 ---
    k_matmul<<<mmgrid, 128, 0, stream>>>(x, W0, H, N, 0);
    k_prop  <<<pgrid, 256, 0, stream>>>(H, row_ptr, col, dinv, b0, 1.f, Cb0, nullptr, N);
    // --- cell1 = Â(relu(cell0) W1) + b1 ---
    k_matmul<<<mmgrid, 128, 0, stream>>>(Cb0, W1, H, N, 1);
    k_prop  <<<pgrid, 256, 0, stream>>>(H, row_ptr, col, dinv, b1, 1.f, Cb1, nullptr, N);
    // --- A = relu(cell0) + relu(cell1); cell2 = Â(A W2) + 2 b2; A += relu(cell2) ---
    k_addrelu2<<<(N * (DIM / 4) + 255) / 256, 256, 0, stream>>>(
        (const float4*)Cb0, (const float4*)Cb1, (float4*)Ab, N * (DIM / 4));
    k_matmul<<<mmgrid, 128, 0, stream>>>(Ab, W2, H, N, 0);
    k_prop  <<<pgrid, 256, 0, stream>>>(H, row_ptr, col, dinv, b2, 2.f, Cb0, Ab, N);
    // --- cell3 = Â(A W3) + 3 b3 ---
    k_matmul<<<mmgrid, 128, 0, stream>>>(Ab, W3, H, N, 0);
    k_prop  <<<pgrid, 256, 0, stream>>>(H, row_ptr, col, dinv, b3, 3.f, Cb1, nullptr, N);
    // --- head: gather labeled rows, log_softmax folded into the C-matmul ---
    k_final<<<(M + 3) / 4, 256, 0, stream>>>(Cb1, labels, Wh, whs, bh, out, M, C);
}

// Round 2
// 660.351 us; speedup vs baseline: 1.5792x; 1.5792x over previous
//
#include <hip/hip_runtime.h>
#include <cstdint>
#include <cstddef>

// Problem constants (from reference): N=50000, E=600000, D=128, C=40, M=25000
#define DIM 128
#define KT  64   // K-chunk for matmul LDS staging

// ---------------------------------------------------------------------------
// CSR build: count in-degrees, prefix-scan, fill column lists
// ---------------------------------------------------------------------------
__global__ void k_count(const int* __restrict__ dst, int* __restrict__ count, int e) {
    int i = blockIdx.x * 256 + threadIdx.x;
    if (i < e) atomicAdd(&count[dst[i]], 1);
}

__global__ void k_dinv(const int* __restrict__ count, float* __restrict__ dinv, int n) {
    int i = blockIdx.x * 256 + threadIdx.x;
    if (i < n) dinv[i] = rsqrtf(1.0f + (float)count[i]);   // deg includes self-loop
}

// Single-block scan: 1024 threads = 16 waves; shuffle scan per wave + LDS wave sums.
// Next chunk's count[] is prefetched before this chunk's barriers so the global
// load latency overlaps the barrier round-trip (was serialized: ~40us -> ~15us).
__global__ __launch_bounds__(1024)
void k_scan(const int* __restrict__ count, int* __restrict__ row_ptr,
            int* __restrict__ cursor, int n) {
    __shared__ int wsum[16];
    __shared__ int s_carry;
    int tid = threadIdx.x;
    int lane = tid & 63, wid = tid >> 6;
    if (tid == 0) s_carry = 0;
    __syncthreads();
    int i = tid;
    int v = (i < n) ? count[i] : 0;
    for (int base = 0; base < n; base += 1024) {
        // prefetch next chunk early (overlaps with scan + barriers below)
        int inext = base + 1024 + tid;
        int vnext = (inext < n) ? count[inext] : 0;
        i = base + tid;
        int x = v;
        #pragma unroll
        for (int off = 1; off < 64; off <<= 1) {
            int y = __shfl_up(x, off, 64);
            if (lane >= off) x += y;
        }
        if (lane == 63) wsum[wid] = x;
        __syncthreads();
        int waveoff = 0, total = 0;
        #pragma unroll
        for (int w = 0; w < 16; ++w) {
            int s = wsum[w];
            if (w < wid) waveoff += s;
            total += s;
        }
        int carry = s_carry;
        int inc = x + waveoff + carry;       // inclusive prefix of count[0..i]
        if (i < n) { row_ptr[i + 1] = inc; cursor[i] = inc - v; }
        __syncthreads();
        if (tid == 0) s_carry = carry + total;
        __syncthreads();
        v = vnext;
    }
    if (tid == 0) row_ptr[0] = 0;
}

__global__ void k_fill(const int* __restrict__ src, const int* __restrict__ dst,
                       int* __restrict__ cursor, int* __restrict__ col, int e) {
    int i = blockIdx.x * 256 + threadIdx.x;
    if (i < e) {
        int d = dst[i];
        int pos = atomicAdd(&cursor[d], 1);
        col[pos] = src[i];
    }
}

// ---------------------------------------------------------------------------
// Matmul v2: out[N,128] = (relu?)in[N,128] @ W[128,128], fp32, register-tiled.
// Block 256 thr = 4 waves; C-tile 128 rows x 128 cols; per-thread 8x8 accums
// (~100 VGPR, no spill -- v1 spilled a 128-reg W slice: 62MB scratch writes).
// A staged TRANSPOSED At[k][row], W natural Bs[k][col]: both frags are
// 2x ds_read_b128. Inner k-step = 4 ds_read_b128 + 64 v_fma_f32 -> FMA-bound.
// LDS 2x32KB per block -> 2 blocks/CU.
// ---------------------------------------------------------------------------
__global__ __launch_bounds__(256)
void k_matmul(const float* __restrict__ in, const float* __restrict__ Wg,
              float* __restrict__ outp, int n, int relu_in) {
    __shared__ float At[KT][DIM];   // [k][row] 32KB
    __shared__ float Bs[KT][DIM];   // [k][col] 32KB
    int tid = threadIdx.x;
    int r0 = blockIdx.x * 128;
    int tx = tid & 15;              // col-group: cols tx*8 .. tx*8+7
    int ty = tid >> 4;              // row-group: rows ty*8 .. ty*8+7

    float acc[8][8];
    #pragma unroll
    for (int i = 0; i < 8; ++i)
        #pragma unroll
        for (int j = 0; j < 8; ++j) acc[i][j] = 0.f;

    for (int kc = 0; kc < DIM; kc += KT) {
        // --- stage A (128 rows x KT ks), transposed; relu on load ---
        {
            int row = tid >> 1;             // 0..127
            int kb  = (tid & 1) * 32;       // 0 or 32
            bool rowok = (r0 + row) < n;
            const float* gA = in + (size_t)(r0 + row) * DIM + kc + kb;
            #pragma unroll
            for (int j = 0; j < 8; ++j) {
                float4 v;
                if (rowok) v = *(const float4*)(gA + 4 * j);
                else { v.x = 0.f; v.y = 0.f; v.z = 0.f; v.w = 0.f; }
                if (relu_in) {
                    v.x = fmaxf(v.x, 0.f); v.y = fmaxf(v.y, 0.f);
                    v.z = fmaxf(v.z, 0.f); v.w = fmaxf(v.w, 0.f);
                }
                int k = kb + 4 * j;
                At[k + 0][row] = v.x;       // bank=row%32: 2-way alias across wave = free
                At[k + 1][row] = v.y;
                At[k + 2][row] = v.z;
                At[k + 3][row] = v.w;
            }
        }
        // --- stage B (KT ks x 128 cols), natural; coalesced float4 ---
        {
            int k  = tid >> 2;              // 0..63
            int cb = (tid & 3) * 32;
            const float* gB = Wg + (size_t)(kc + k) * DIM + cb;
            #pragma unroll
            for (int j = 0; j < 8; ++j)
                *(float4*)&Bs[k][cb + 4 * j] = *(const float4*)(gB + 4 * j);
        }
        __syncthreads();

        #pragma unroll 2
        for (int k = 0; k < KT; ++k) {
            float4 a0 = *(const float4*)&At[k][ty * 8];
            float4 a1 = *(const float4*)&At[k][ty * 8 + 4];
            float4 b0 = *(const float4*)&Bs[k][tx * 8];
            float4 b1 = *(const float4*)&Bs[k][tx * 8 + 4];
            float a[8] = {a0.x, a0.y, a0.z, a0.w, a1.x, a1.y, a1.z, a1.w};
            float b[8] = {b0.x, b0.y, b0.z, b0.w, b1.x, b1.y, b1.z, b1.w};
            #pragma unroll
            for (int i = 0; i < 8; ++i)
                #pragma unroll
                for (int j = 0; j < 8; ++j)
                    acc[i][j] = fmaf(a[i], b[j], acc[i][j]);
        }
        __syncthreads();
    }

    // --- store 8x8 tile, 2x float4 per row, coalesced across tx ---
    #pragma unroll
    for (int i = 0; i < 8; ++i) {
        int r = r0 + ty * 8 + i;
        if (r < n) {
            float4 o0, o1;
            o0.x = acc[i][0]; o0.y = acc[i][1]; o0.z = acc[i][2]; o0.w = acc[i][3];
            o1.x = acc[i][4]; o1.y = acc[i][5]; o1.z = acc[i][6]; o1.w = acc[i][7];
            float* gO = outp + (size_t)r * DIM + tx * 8;
            *(float4*)gO = o0;
            *(float4*)(gO + 4) = o1;
        }
    }
}

// ---------------------------------------------------------------------------
// Propagation: out[d] = sum_{e: dst=d} dinv[src]*dinv[d]*h[src] + dinv[d]^2*h[d]
//              + bscale*bias.  One wave per dst node, 2 floats per lane.
// Optionally accum[d] += relu(out[d])  (fused for the cell3 input sum).
// ---------------------------------------------------------------------------
__global__ __launch_bounds__(256)
void k_prop(const float* __restrict__ h, const int* __restrict__ row_ptr,
            const int* __restrict__ col, const float* __restrict__ dinv,
            const float* __restrict__ bias, float bscale,
            float* __restrict__ outp, float* __restrict__ accum, int n) {
    int wid  = (blockIdx.x * 256 + threadIdx.x) >> 6;
    int lane = threadIdx.x & 63;
    if (wid >= n) return;
    int beg = row_ptr[wid], end = row_ptr[wid + 1];
    float di = dinv[wid];
    const float2* h2 = (const float2*)h;
    float ax = 0.f, ay = 0.f;
    int j = beg;
    int s_next = (j < end) ? col[j] : 0;
    for (; j < end; ) {
        int s = s_next;
        ++j;
        s_next = (j < end) ? col[j] : 0;   // prefetch next column index
        float wgt = dinv[s] * di;
        float2 v = h2[(size_t)s * 64 + lane];
        ax = fmaf(wgt, v.x, ax);
        ay = fmaf(wgt, v.y, ay);
    }
    float2 sv = h2[(size_t)wid * 64 + lane];
    float w2 = di * di;
    ax = fmaf(w2, sv.x, ax);
    ay = fmaf(w2, sv.y, ay);
    float2 b = ((const float2*)bias)[lane];
    ax += bscale * b.x;
    ay += bscale * b.y;
    float2 o; o.x = ax; o.y = ay;
    ((float2*)outp)[(size_t)wid * 64 + lane] = o;
    if (accum) {
        float2* a2 = (float2*)accum + (size_t)wid * 64 + lane;
        float2 av = *a2;
        av.x += fmaxf(ax, 0.f);
        av.y += fmaxf(ay, 0.f);
        *a2 = av;
    }
}

// A = relu(c0) + relu(c1), elementwise float4
__global__ void k_addrelu2(const float4* __restrict__ a, const float4* __restrict__ b,
                           float4* __restrict__ o, int n4) {
    int i = blockIdx.x * 256 + threadIdx.x;
    if (i < n4) {
        float4 x = a[i], y = b[i], r;
        r.x = fmaxf(x.x, 0.f) + fmaxf(y.x, 0.f);
        r.y = fmaxf(x.y, 0.f) + fmaxf(y.y, 0.f);
        r.z = fmaxf(x.z, 0.f) + fmaxf(y.z, 0.f);
        r.w = fmaxf(x.w, 0.f) + fmaxf(y.w, 0.f);
        o[i] = r;
    }
}

// column sums of Wh [128,40]
__global__ void k_whsum(const float* __restrict__ Wh, float* __restrict__ whs, int C) {
    int c = threadIdx.x;
    if (c < C) {
        float s = 0.f;
        for (int d = 0; d < DIM; ++d) s += Wh[d * C + c];
        whs[c] = s;
    }
}

// pred[m,c] = sum_d v_d Wh[d,c] - L*whsum[c] + bh[c],  L = max + log(sum exp(v-max))
// One wave per label row.
__global__ __launch_bounds__(256)
void k_final(const float* __restrict__ C3, const int* __restrict__ labels,
             const float* __restrict__ Wh, const float* __restrict__ whs,
             const float* __restrict__ bh, float* __restrict__ outp,
             int m_total, int C) {
    __shared__ float vl[4][DIM];
    int wid = threadIdx.x >> 6, lane = threadIdx.x & 63;
    int m = blockIdx.x * 4 + wid;
    if (m >= m_total) return;
    int row = labels[m];
    float2 v = ((const float2*)(C3 + (size_t)row * DIM))[lane];
    float mx = fmaxf(v.x, v.y);
    #pragma unroll
    for (int off = 32; off > 0; off >>= 1) mx = fmaxf(mx, __shfl_xor(mx, off, 64));
    float s = expf(v.x - mx) + expf(v.y - mx);
    #pragma unroll
    for (int off = 32; off > 0; off >>= 1) s += __shfl_xor(s, off, 64);
    float L = mx + logf(s);
    vl[wid][2 * lane]     = v.x;
    vl[wid][2 * lane + 1] = v.y;
    // same-wave LDS RAW: compiler inserts the required lgkmcnt wait
    if (lane < C) {
        float acc = 0.f;
        #pragma unroll 8
        for (int d = 0; d < DIM; ++d)
            acc = fmaf(vl[wid][d], Wh[d * C + lane], acc);
        outp[(size_t)m * C + lane] = acc - L * whs[lane] + bh[lane];
    }
}

// ---------------------------------------------------------------------------
extern "C" void kernel_launch(void* const* d_in, const int* in_sizes, int n_in,
                              void* d_out, int out_size, void* d_ws, size_t ws_size,
                              hipStream_t stream) {
    const float* x      = (const float*)d_in[0];
    const int*   edges  = (const int*)d_in[1];
    const int*   labels = (const int*)d_in[2];
    const float* W0 = (const float*)d_in[3];
    const float* b0 = (const float*)d_in[4];
    const float* W1 = (const float*)d_in[5];
    const float* b1 = (const float*)d_in[6];
    const float* W2 = (const float*)d_in[7];
    const float* b2 = (const float*)d_in[8];
    const float* W3 = (const float*)d_in[9];
    const float* b3 = (const float*)d_in[10];
    const float* Wh = (const float*)d_in[11];
    const float* bh = (const float*)d_in[12];
    float* out = (float*)d_out;

    const int N = in_sizes[0] / DIM;       // 50000
    const int E = in_sizes[1] / 2;         // 600000
    const int M = in_sizes[2];             // 25000
    const int C = in_sizes[12];            // 40

    // Workspace layout (256B-aligned slices)
    char* ws = (char*)d_ws;
    auto alloc = [&](size_t bytes) {
        char* p = ws;
        ws += (bytes + 255) & ~(size_t)255;
        return p;
    };
    float* dinv    = (float*)alloc((size_t)N * 4);
    int*   count   = (int*)  alloc((size_t)N * 4);
    int*   row_ptr = (int*)  alloc((size_t)(N + 1) * 4);
    int*   cursor  = (int*)  alloc((size_t)N * 4);
    int*   col     = (int*)  alloc((size_t)E * 4);
    float* whs     = (float*)alloc(256);
    float* H   = (float*)alloc((size_t)N * DIM * 4);
    float* Cb0 = (float*)alloc((size_t)N * DIM * 4);   // holds cell0, later cell2
    float* Cb1 = (float*)alloc((size_t)N * DIM * 4);   // holds cell1, later cell3
    float* Ab  = (float*)alloc((size_t)N * DIM * 4);   // running relu-sum

    const int* src = edges;
    const int* dst = edges + E;

    int egrid = (E + 255) / 256;
    int ngrid = (N + 255) / 256;
    int mmgrid = (N + 127) / 128;          // 128-row C-tiles
    int pgrid  = (N + 3) / 4;              // one wave per node, 4 waves/block

    // --- CSR build ---
    hipMemsetAsync(count, 0, (size_t)N * 4, stream);
    k_count<<<egrid, 256, 0, stream>>>(dst, count, E);
    k_dinv <<<ngrid, 256, 0, stream>>>(count, dinv, N);
    k_scan <<<1, 1024, 0, stream>>>(count, row_ptr, cursor, N);
    k_fill <<<egrid, 256, 0, stream>>>(src, dst, cursor, col, E);
    k_whsum<<<1, 64, 0, stream>>>(Wh, whs, C);

    // --- cell0 = Â(x W0) + b0 ---
    k_matmul<<<mmgrid, 256, 0, stream>>>(x, W0, H, N, 0);
    k_prop  <<<pgrid, 256, 0, stream>>>(H, row_ptr, col, dinv, b0, 1.f, Cb0, nullptr, N);
    // --- cell1 = Â(relu(cell0) W1) + b1 ---
    k_matmul<<<mmgrid, 256, 0, stream>>>(Cb0, W1, H, N, 1);
    k_prop  <<<pgrid, 256, 0, stream>>>(H, row_ptr, col, dinv, b1, 1.f, Cb1, nullptr, N);
    // --- A = relu(cell0) + relu(cell1); cell2 = Â(A W2) + 2 b2; A += relu(cell2) ---
    k_addrelu2<<<(N * (DIM / 4) + 255) / 256, 256, 0, stream>>>(
        (const float4*)Cb0, (const float4*)Cb1, (float4*)Ab, N * (DIM / 4));
    k_matmul<<<mmgrid, 256, 0, stream>>>(Ab, W2, H, N, 0);
    k_prop  <<<pgrid, 256, 0, stream>>>(H, row_ptr, col, dinv, b2, 2.f, Cb0, Ab, N);
    // --- cell3 = Â(A W3) + 3 b3 ---
    k_matmul<<<mmgrid, 256, 0, stream>>>(Ab, W3, H, N, 0);
    k_prop  <<<pgrid, 256, 0, stream>>>(H, row_ptr, col, dinv, b3, 3.f, Cb1, nullptr, N);
    // --- head: gather labeled rows, log_softmax folded into the C-matmul ---
    k_final<<<(M + 3) / 4, 256, 0, stream>>>(Cb1, labels, Wh, whs, bh, out, M, C);
}

// Round 3
// 537.137 us; speedup vs baseline: 1.9415x; 1.2294x over previous
//
#include <hip/hip_runtime.h>
#include <cstdint>
#include <cstddef>

// Problem constants (from reference): N=50000, E=600000, D=128, C=40, M=25000
#define DIM 128
#define KT  64   // K-chunk for matmul LDS staging

// ---------------------------------------------------------------------------
// CSR build: count in-degrees, prefix-scan (+dinv fused), fill column lists
// ---------------------------------------------------------------------------
__global__ void k_count(const int* __restrict__ dst, int* __restrict__ count, int e) {
    int i = blockIdx.x * 256 + threadIdx.x;
    if (i < e) atomicAdd(&count[dst[i]], 1);
}

// Single-block scan: 1024 threads = 16 waves; shuffle scan per wave + LDS wave sums.
// Next chunk prefetched before this chunk's barriers; dinv computed inline.
__global__ __launch_bounds__(1024)
void k_scan(const int* __restrict__ count, int* __restrict__ row_ptr,
            int* __restrict__ cursor, float* __restrict__ dinv, int n) {
    __shared__ int wsum[16];
    __shared__ int s_carry;
    int tid = threadIdx.x;
    int lane = tid & 63, wid = tid >> 6;
    if (tid == 0) s_carry = 0;
    __syncthreads();
    int i = tid;
    int v = (i < n) ? count[i] : 0;
    for (int base = 0; base < n; base += 1024) {
        int inext = base + 1024 + tid;
        int vnext = (inext < n) ? count[inext] : 0;   // prefetch next chunk
        i = base + tid;
        if (i < n) dinv[i] = rsqrtf(1.0f + (float)v); // deg includes self-loop
        int x = v;
        #pragma unroll
        for (int off = 1; off < 64; off <<= 1) {
            int y = __shfl_up(x, off, 64);
            if (lane >= off) x += y;
        }
        if (lane == 63) wsum[wid] = x;
        __syncthreads();
        int waveoff = 0, total = 0;
        #pragma unroll
        for (int w = 0; w < 16; ++w) {
            int s = wsum[w];
            if (w < wid) waveoff += s;
            total += s;
        }
        int carry = s_carry;
        int inc = x + waveoff + carry;       // inclusive prefix of count[0..i]
        if (i < n) { row_ptr[i + 1] = inc; cursor[i] = inc - v; }
        __syncthreads();
        if (tid == 0) s_carry = carry + total;
        __syncthreads();
        v = vnext;
    }
    if (tid == 0) row_ptr[0] = 0;
}

__global__ void k_fill(const int* __restrict__ src, const int* __restrict__ dst,
                       int* __restrict__ cursor, int* __restrict__ col, int e) {
    int i = blockIdx.x * 256 + threadIdx.x;
    if (i < e) {
        int d = dst[i];
        int pos = atomicAdd(&cursor[d], 1);
        col[pos] = src[i];
    }
}

// ---------------------------------------------------------------------------
// Matmul: out[N,128] = in[N,128] @ W[128,128], fp32, register-tiled.
// Block 256 thr; C-tile 128x128; 8x8 accums/thread (~100 VGPR, no spill).
// ---------------------------------------------------------------------------
__global__ __launch_bounds__(256)
void k_matmul(const float* __restrict__ in, const float* __restrict__ Wg,
              float* __restrict__ outp, int n) {
    __shared__ float At[KT][DIM];   // [k][row] 32KB
    __shared__ float Bs[KT][DIM];   // [k][col] 32KB
    int tid = threadIdx.x;
    int r0 = blockIdx.x * 128;
    int tx = tid & 15;              // col-group: cols tx*8 .. tx*8+7
    int ty = tid >> 4;              // row-group: rows ty*8 .. ty*8+7

    float acc[8][8];
    #pragma unroll
    for (int i = 0; i < 8; ++i)
        #pragma unroll
        for (int j = 0; j < 8; ++j) acc[i][j] = 0.f;

    for (int kc = 0; kc < DIM; kc += KT) {
        {   // stage A (128 rows x KT ks), transposed
            int row = tid >> 1;             // 0..127
            int kb  = (tid & 1) * 32;       // 0 or 32
            bool rowok = (r0 + row) < n;
            const float* gA = in + (size_t)(r0 + row) * DIM + kc + kb;
            #pragma unroll
            for (int j = 0; j < 8; ++j) {
                float4 v;
                if (rowok) v = *(const float4*)(gA + 4 * j);
                else { v.x = 0.f; v.y = 0.f; v.z = 0.f; v.w = 0.f; }
                int k = kb + 4 * j;
                At[k + 0][row] = v.x;       // 2-way bank alias across wave = free
                At[k + 1][row] = v.y;
                At[k + 2][row] = v.z;
                At[k + 3][row] = v.w;
            }
        }
        {   // stage B (KT ks x 128 cols), natural; coalesced float4
            int k  = tid >> 2;              // 0..63
            int cb = (tid & 3) * 32;
            const float* gB = Wg + (size_t)(kc + k) * DIM + cb;
            #pragma unroll
            for (int j = 0; j < 8; ++j)
                *(float4*)&Bs[k][cb + 4 * j] = *(const float4*)(gB + 4 * j);
        }
        __syncthreads();

        #pragma unroll 2
        for (int k = 0; k < KT; ++k) {
            float4 a0 = *(const float4*)&At[k][ty * 8];
            float4 a1 = *(const float4*)&At[k][ty * 8 + 4];
            float4 b0 = *(const float4*)&Bs[k][tx * 8];
            float4 b1 = *(const float4*)&Bs[k][tx * 8 + 4];
            float a[8] = {a0.x, a0.y, a0.z, a0.w, a1.x, a1.y, a1.z, a1.w};
            float b[8] = {b0.x, b0.y, b0.z, b0.w, b1.x, b1.y, b1.z, b1.w};
            #pragma unroll
            for (int i = 0; i < 8; ++i)
                #pragma unroll
                for (int j = 0; j < 8; ++j)
                    acc[i][j] = fmaf(a[i], b[j], acc[i][j]);
        }
        __syncthreads();
    }

    #pragma unroll
    for (int i = 0; i < 8; ++i) {
        int r = r0 + ty * 8 + i;
        if (r < n) {
            float4 o0, o1;
            o0.x = acc[i][0]; o0.y = acc[i][1]; o0.z = acc[i][2]; o0.w = acc[i][3];
            o1.x = acc[i][4]; o1.y = acc[i][5]; o1.z = acc[i][6]; o1.w = acc[i][7];
            float* gO = outp + (size_t)r * DIM + tx * 8;
            *(float4*)gO = o0;
            *(float4*)(gO + 4) = o1;
        }
    }
}

// ---------------------------------------------------------------------------
// Propagation, MLP-unrolled x4. One wave per dst node, float2 per lane.
//   res = relu( di*sum_{e} dinv[src]*h[src] + di^2*h[node] + bscale*bias )
//   out[node] = (addin ? addin[node] : 0) + res
// addin==outp (in-place accumulate) is allowed: each wave only touches its row.
// ---------------------------------------------------------------------------
__global__ __launch_bounds__(256)
void k_prop(const float* __restrict__ h, const int* __restrict__ row_ptr,
            const int* __restrict__ col, const float* __restrict__ dinv,
            const float* __restrict__ bias, float bscale,
            const float* addin, float* outp, int n) {
    int node = (blockIdx.x * 256 + threadIdx.x) >> 6;
    int lane = threadIdx.x & 63;
    if (node >= n) return;
    int beg = row_ptr[node], end = row_ptr[node + 1];
    float di = dinv[node];
    const float2* h2 = (const float2*)h;
    float ax = 0.f, ay = 0.f, bx = 0.f, by = 0.f;
    int j = beg;
    // 4 independent edge loads in flight (2 dependence levels per 4 edges,
    // vs 8 when walked one at a time -> latency-bound 77us -> BW-bound)
    for (; j + 4 <= end; j += 4) {
        int s0 = col[j], s1 = col[j + 1], s2 = col[j + 2], s3 = col[j + 3];
        float w0 = dinv[s0], w1 = dinv[s1], w2 = dinv[s2], w3 = dinv[s3];
        float2 v0 = h2[(size_t)s0 * 64 + lane];
        float2 v1 = h2[(size_t)s1 * 64 + lane];
        float2 v2 = h2[(size_t)s2 * 64 + lane];
        float2 v3 = h2[(size_t)s3 * 64 + lane];
        ax = fmaf(w0, v0.x, ax); ay = fmaf(w0, v0.y, ay);
        bx = fmaf(w1, v1.x, bx); by = fmaf(w1, v1.y, by);
        ax = fmaf(w2, v2.x, ax); ay = fmaf(w2, v2.y, ay);
        bx = fmaf(w3, v3.x, bx); by = fmaf(w3, v3.y, by);
    }
    for (; j < end; ++j) {
        int s = col[j];
        float w = dinv[s];
        float2 v = h2[(size_t)s * 64 + lane];
        ax = fmaf(w, v.x, ax); ay = fmaf(w, v.y, ay);
    }
    ax += bx; ay += by;
    float2 sv = h2[(size_t)node * 64 + lane];
    // di*(sum + di*self) = di*sum(dinv[s]h[s]) + di^2*h[node]
    float rx = di * fmaf(di, sv.x, ax);
    float ry = di * fmaf(di, sv.y, ay);
    float2 b = ((const float2*)bias)[lane];
    rx = fmaf(bscale, b.x, rx);
    ry = fmaf(bscale, b.y, ry);
    rx = fmaxf(rx, 0.f);                    // cells 0..2 only consumed via relu
    ry = fmaxf(ry, 0.f);
    if (addin) {
        float2 av = ((const float2*)addin)[(size_t)node * 64 + lane];
        rx += av.x; ry += av.y;
    }
    float2 o; o.x = rx; o.y = ry;
    ((float2*)outp)[(size_t)node * 64 + lane] = o;
}

// ---------------------------------------------------------------------------
// Fused prop(cell3) + log_softmax + head, over the M label rows only.
// cell3 is never materialized. One wave per label row.
// pred[m,c] = sum_d v_d Wh[d,c] - L*whsum[c] + bh[c], L = logsumexp(v)
// ---------------------------------------------------------------------------
__global__ __launch_bounds__(256)
void k_prop_final(const float* __restrict__ h, const int* __restrict__ row_ptr,
                  const int* __restrict__ col, const float* __restrict__ dinv,
                  const float* __restrict__ bias, float bscale,
                  const int* __restrict__ labels,
                  const float* __restrict__ Wh, const float* __restrict__ whs,
                  const float* __restrict__ bh, float* __restrict__ outp,
                  int m_total, int C) {
    __shared__ float vl[4][DIM];
    int wslot = threadIdx.x >> 6, lane = threadIdx.x & 63;
    int m = blockIdx.x * 4 + wslot;
    if (m >= m_total) return;
    int node = labels[m];
    int beg = row_ptr[node], end = row_ptr[node + 1];
    float di = dinv[node];
    const float2* h2 = (const float2*)h;
    float ax = 0.f, ay = 0.f, bx = 0.f, by = 0.f;
    int j = beg;
    for (; j + 4 <= end; j += 4) {
        int s0 = col[j], s1 = col[j + 1], s2 = col[j + 2], s3 = col[j + 3];
        float w0 = dinv[s0], w1 = dinv[s1], w2 = dinv[s2], w3 = dinv[s3];
        float2 v0 = h2[(size_t)s0 * 64 + lane];
        float2 v1 = h2[(size_t)s1 * 64 + lane];
        float2 v2 = h2[(size_t)s2 * 64 + lane];
        float2 v3 = h2[(size_t)s3 * 64 + lane];
        ax = fmaf(w0, v0.x, ax); ay = fmaf(w0, v0.y, ay);
        bx = fmaf(w1, v1.x, bx); by = fmaf(w1, v1.y, by);
        ax = fmaf(w2, v2.x, ax); ay = fmaf(w2, v2.y, ay);
        bx = fmaf(w3, v3.x, bx); by = fmaf(w3, v3.y, by);
    }
    for (; j < end; ++j) {
        int s = col[j];
        float w = dinv[s];
        float2 v = h2[(size_t)s * 64 + lane];
        ax = fmaf(w, v.x, ax); ay = fmaf(w, v.y, ay);
    }
    ax += bx; ay += by;
    float2 sv = h2[(size_t)node * 64 + lane];
    float vx = di * fmaf(di, sv.x, ax);
    float vy = di * fmaf(di, sv.y, ay);
    float2 b = ((const float2*)bias)[lane];
    vx = fmaf(bscale, b.x, vx);
    vy = fmaf(bscale, b.y, vy);
    // logsumexp over the 128 features of this row
    float mx = fmaxf(vx, vy);
    #pragma unroll
    for (int off = 32; off > 0; off >>= 1) mx = fmaxf(mx, __shfl_xor(mx, off, 64));
    float s = expf(vx - mx) + expf(vy - mx);
    #pragma unroll
    for (int off = 32; off > 0; off >>= 1) s += __shfl_xor(s, off, 64);
    float L = mx + logf(s);
    vl[wslot][2 * lane]     = vx;
    vl[wslot][2 * lane + 1] = vy;
    // same-wave LDS RAW: compiler inserts the required lgkmcnt wait
    if (lane < C) {
        float acc = 0.f;
        #pragma unroll 8
        for (int d = 0; d < DIM; ++d)
            acc = fmaf(vl[wslot][d], Wh[d * C + lane], acc);
        outp[(size_t)m * C + lane] = acc - L * whs[lane] + bh[lane];
    }
}

// column sums of Wh [128,40]
__global__ void k_whsum(const float* __restrict__ Wh, float* __restrict__ whs, int C) {
    int c = threadIdx.x;
    if (c < C) {
        float s = 0.f;
        for (int d = 0; d < DIM; ++d) s += Wh[d * C + c];
        whs[c] = s;
    }
}

// ---------------------------------------------------------------------------
extern "C" void kernel_launch(void* const* d_in, const int* in_sizes, int n_in,
                              void* d_out, int out_size, void* d_ws, size_t ws_size,
                              hipStream_t stream) {
    const float* x      = (const float*)d_in[0];
    const int*   edges  = (const int*)d_in[1];
    const int*   labels = (const int*)d_in[2];
    const float* W0 = (const float*)d_in[3];
    const float* b0 = (const float*)d_in[4];
    const float* W1 = (const float*)d_in[5];
    const float* b1 = (const float*)d_in[6];
    const float* W2 = (const float*)d_in[7];
    const float* b2 = (const float*)d_in[8];
    const float* W3 = (const float*)d_in[9];
    const float* b3 = (const float*)d_in[10];
    const float* Wh = (const float*)d_in[11];
    const float* bh = (const float*)d_in[12];
    float* out = (float*)d_out;

    const int N = in_sizes[0] / DIM;       // 50000
    const int E = in_sizes[1] / 2;         // 600000
    const int M = in_sizes[2];             // 25000
    const int C = in_sizes[12];            // 40

    // Workspace layout (256B-aligned slices)
    char* ws = (char*)d_ws;
    auto alloc = [&](size_t bytes) {
        char* p = ws;
        ws += (bytes + 255) & ~(size_t)255;
        return p;
    };
    float* dinv    = (float*)alloc((size_t)N * 4);
    int*   count   = (int*)  alloc((size_t)N * 4);
    int*   row_ptr = (int*)  alloc((size_t)(N + 1) * 4);
    int*   cursor  = (int*)  alloc((size_t)N * 4);
    int*   col     = (int*)  alloc((size_t)E * 4);
    float* whs     = (float*)alloc(256);
    float* H  = (float*)alloc((size_t)N * DIM * 4);   // matmul output (all layers)
    float* R0 = (float*)alloc((size_t)N * DIM * 4);   // relu(cell0)
    float* A  = (float*)alloc((size_t)N * DIM * 4);   // running relu-sum

    const int* src = edges;
    const int* dst = edges + E;

    int egrid  = (E + 255) / 256;
    int mmgrid = (N + 127) / 128;          // 128-row C-tiles
    int pgrid  = (N + 3) / 4;              // one wave per node, 4 waves/block

    // --- CSR build ---
    hipMemsetAsync(count, 0, (size_t)N * 4, stream);
    k_count<<<egrid, 256, 0, stream>>>(dst, count, E);
    k_scan <<<1, 1024, 0, stream>>>(count, row_ptr, cursor, dinv, N);
    k_fill <<<egrid, 256, 0, stream>>>(src, dst, cursor, col, E);
    k_whsum<<<1, 64, 0, stream>>>(Wh, whs, C);

    // --- R0 = relu(cell0) = relu(Â(x W0) + b0) ---
    k_matmul<<<mmgrid, 256, 0, stream>>>(x, W0, H, N);
    k_prop  <<<pgrid, 256, 0, stream>>>(H, row_ptr, col, dinv, b0, 1.f, nullptr, R0, N);
    // --- A = R0 + relu(cell1),  cell1 = Â(R0 W1) + b1 ---
    k_matmul<<<mmgrid, 256, 0, stream>>>(R0, W1, H, N);
    k_prop  <<<pgrid, 256, 0, stream>>>(H, row_ptr, col, dinv, b1, 1.f, R0, A, N);
    // --- A += relu(cell2),  cell2 = Â(A W2) + 2 b2  (in-place row-local) ---
    k_matmul<<<mmgrid, 256, 0, stream>>>(A, W2, H, N);
    k_prop  <<<pgrid, 256, 0, stream>>>(H, row_ptr, col, dinv, b2, 2.f, A, A, N);
    // --- head over labels only: cell3 = Â(A W3) + 3 b3, never materialized ---
    k_matmul<<<mmgrid, 256, 0, stream>>>(A, W3, H, N);
    k_prop_final<<<(M + 3) / 4, 256, 0, stream>>>(H, row_ptr, col, dinv, b3, 3.f,
                                                  labels, Wh, whs, bh, out, M, C);
}

// Round 4
// 489.362 us; speedup vs baseline: 2.1310x; 1.0976x over previous
//
#include <hip/hip_runtime.h>
#include <cstdint>
#include <cstddef>

// Problem constants (from reference): N=50000, E=600000, D=128, C=40, M=25000
#define DIM 128
#define KT  64   // K-chunk for matmul LDS staging

// ---------------------------------------------------------------------------
// CSR build: count in-degrees, parallel scan (+dinv fused), fill column lists
// ---------------------------------------------------------------------------
__global__ void k_count(const int* __restrict__ dst, int* __restrict__ count, int e) {
    int i = blockIdx.x * 256 + threadIdx.x;
    if (i < e) atomicAdd(&count[dst[i]], 1);
}

// Parallel scan pass A: per-block (1024-elem) inclusive scan -> partial[],
// block totals -> bsum[]. dinv computed inline. Replaces the old sequential
// single-block scan (49 serial iterations x store-drain+barrier = 55us).
__global__ __launch_bounds__(1024)
void k_scanA(const int* __restrict__ count, int* __restrict__ partial,
             int* __restrict__ bsum, float* __restrict__ dinv, int n) {
    __shared__ int wsum[16];
    int tid = threadIdx.x, lane = tid & 63, wid = tid >> 6;
    int i = blockIdx.x * 1024 + tid;
    int v = (i < n) ? count[i] : 0;
    if (i < n) dinv[i] = rsqrtf(1.0f + (float)v);   // deg includes self-loop
    int x = v;
    #pragma unroll
    for (int off = 1; off < 64; off <<= 1) {
        int y = __shfl_up(x, off, 64);
        if (lane >= off) x += y;
    }
    if (lane == 63) wsum[wid] = x;
    __syncthreads();
    int waveoff = 0, total = 0;
    #pragma unroll
    for (int w = 0; w < 16; ++w) {
        int s = wsum[w];
        if (w < wid) waveoff += s;
        total += s;
    }
    if (i < n) partial[i] = x + waveoff;            // block-local inclusive
    if (tid == 0) bsum[blockIdx.x] = total;
}

// Pass B: each block computes its global offset by wave-reducing the preceding
// block totals (nb <= 64 per 64-chunk, looped with carry), then emits
// row_ptr (inclusive, shifted) and cursor (exclusive).
__global__ __launch_bounds__(1024)
void k_scanB(const int* __restrict__ count, const int* __restrict__ partial,
             const int* __restrict__ bsum, int* __restrict__ row_ptr,
             int* __restrict__ cursor, int n, int nb) {
    __shared__ int s_off;
    int tid = threadIdx.x;
    if (tid < 64) {
        int carry = 0;
        for (int base = 0; base < nb; base += 64) {
            int idx = base + tid;
            int v = (idx < nb && idx < blockIdx.x) ? bsum[idx] : 0;
            #pragma unroll
            for (int off = 32; off > 0; off >>= 1) v += __shfl_xor(v, off, 64);
            carry += v;
        }
        if (tid == 0) s_off = carry;
    }
    __syncthreads();
    int off = s_off;
    int i = blockIdx.x * 1024 + tid;
    if (i < n) {
        int inc = partial[i] + off;
        row_ptr[i + 1] = inc;
        cursor[i] = inc - count[i];
    }
    if (blockIdx.x == 0 && tid == 0) row_ptr[0] = 0;
}

__global__ void k_fill(const int* __restrict__ src, const int* __restrict__ dst,
                       int* __restrict__ cursor, int* __restrict__ col, int e) {
    int i = blockIdx.x * 256 + threadIdx.x;
    if (i < e) {
        int d = dst[i];
        int pos = atomicAdd(&cursor[d], 1);
        col[pos] = src[i];
    }
}

// ---------------------------------------------------------------------------
// Matmul: out[N,128] = in[N,128] @ W[128,128], fp32, register-tiled.
// Block 256 thr; C-tile 128x128; 8x8 accums/thread (~100 VGPR, no spill).
// ---------------------------------------------------------------------------
__global__ __launch_bounds__(256)
void k_matmul(const float* __restrict__ in, const float* __restrict__ Wg,
              float* __restrict__ outp, int n) {
    __shared__ float At[KT][DIM];   // [k][row] 32KB
    __shared__ float Bs[KT][DIM];   // [k][col] 32KB
    int tid = threadIdx.x;
    int r0 = blockIdx.x * 128;
    int tx = tid & 15;              // col-group: cols tx*8 .. tx*8+7
    int ty = tid >> 4;              // row-group: rows ty*8 .. ty*8+7

    float acc[8][8];
    #pragma unroll
    for (int i = 0; i < 8; ++i)
        #pragma unroll
        for (int j = 0; j < 8; ++j) acc[i][j] = 0.f;

    for (int kc = 0; kc < DIM; kc += KT) {
        {   // stage A (128 rows x KT ks), transposed
            int row = tid >> 1;             // 0..127
            int kb  = (tid & 1) * 32;       // 0 or 32
            bool rowok = (r0 + row) < n;
            const float* gA = in + (size_t)(r0 + row) * DIM + kc + kb;
            #pragma unroll
            for (int j = 0; j < 8; ++j) {
                float4 v;
                if (rowok) v = *(const float4*)(gA + 4 * j);
                else { v.x = 0.f; v.y = 0.f; v.z = 0.f; v.w = 0.f; }
                int k = kb + 4 * j;
                At[k + 0][row] = v.x;       // 2-way bank alias across wave = free
                At[k + 1][row] = v.y;
                At[k + 2][row] = v.z;
                At[k + 3][row] = v.w;
            }
        }
        {   // stage B (KT ks x 128 cols), natural; coalesced float4
            int k  = tid >> 2;              // 0..63
            int cb = (tid & 3) * 32;
            const float* gB = Wg + (size_t)(kc + k) * DIM + cb;
            #pragma unroll
            for (int j = 0; j < 8; ++j)
                *(float4*)&Bs[k][cb + 4 * j] = *(const float4*)(gB + 4 * j);
        }
        __syncthreads();

        #pragma unroll 2
        for (int k = 0; k < KT; ++k) {
            float4 a0 = *(const float4*)&At[k][ty * 8];
            float4 a1 = *(const float4*)&At[k][ty * 8 + 4];
            float4 b0 = *(const float4*)&Bs[k][tx * 8];
            float4 b1 = *(const float4*)&Bs[k][tx * 8 + 4];
            float a[8] = {a0.x, a0.y, a0.z, a0.w, a1.x, a1.y, a1.z, a1.w};
            float b[8] = {b0.x, b0.y, b0.z, b0.w, b1.x, b1.y, b1.z, b1.w};
            #pragma unroll
            for (int i = 0; i < 8; ++i)
                #pragma unroll
                for (int j = 0; j < 8; ++j)
                    acc[i][j] = fmaf(a[i], b[j], acc[i][j]);
        }
        __syncthreads();
    }

    #pragma unroll
    for (int i = 0; i < 8; ++i) {
        int r = r0 + ty * 8 + i;
        if (r < n) {
            float4 o0, o1;
            o0.x = acc[i][0]; o0.y = acc[i][1]; o0.z = acc[i][2]; o0.w = acc[i][3];
            o1.x = acc[i][4]; o1.y = acc[i][5]; o1.z = acc[i][6]; o1.w = acc[i][7];
            float* gO = outp + (size_t)r * DIM + tx * 8;
            *(float4*)gO = o0;
            *(float4*)(gO + 4) = o1;
        }
    }
}

// ---------------------------------------------------------------------------
// Propagation, MLP-unrolled x4. One wave per dst node, float2 per lane.
//   res = relu( di*sum_{e} dinv[src]*h[src] + di^2*h[node] + bscale*bias )
//   out[node] = (addin ? addin[node] : 0) + res
// addin==outp (in-place accumulate) is allowed: each wave only touches its row.
// ---------------------------------------------------------------------------
__global__ __launch_bounds__(256)
void k_prop(const float* __restrict__ h, const int* __restrict__ row_ptr,
            const int* __restrict__ col, const float* __restrict__ dinv,
            const float* __restrict__ bias, float bscale,
            const float* addin, float* outp, int n) {
    int node = (blockIdx.x * 256 + threadIdx.x) >> 6;
    int lane = threadIdx.x & 63;
    if (node >= n) return;
    int beg = row_ptr[node], end = row_ptr[node + 1];
    float di = dinv[node];
    const float2* h2 = (const float2*)h;
    float ax = 0.f, ay = 0.f, bx = 0.f, by = 0.f;
    int j = beg;
    // 4 independent edge loads in flight (2 dependence levels per 4 edges)
    for (; j + 4 <= end; j += 4) {
        int s0 = col[j], s1 = col[j + 1], s2 = col[j + 2], s3 = col[j + 3];
        float w0 = dinv[s0], w1 = dinv[s1], w2 = dinv[s2], w3 = dinv[s3];
        float2 v0 = h2[(size_t)s0 * 64 + lane];
        float2 v1 = h2[(size_t)s1 * 64 + lane];
        float2 v2 = h2[(size_t)s2 * 64 + lane];
        float2 v3 = h2[(size_t)s3 * 64 + lane];
        ax = fmaf(w0, v0.x, ax); ay = fmaf(w0, v0.y, ay);
        bx = fmaf(w1, v1.x, bx); by = fmaf(w1, v1.y, by);
        ax = fmaf(w2, v2.x, ax); ay = fmaf(w2, v2.y, ay);
        bx = fmaf(w3, v3.x, bx); by = fmaf(w3, v3.y, by);
    }
    for (; j < end; ++j) {
        int s = col[j];
        float w = dinv[s];
        float2 v = h2[(size_t)s * 64 + lane];
        ax = fmaf(w, v.x, ax); ay = fmaf(w, v.y, ay);
    }
    ax += bx; ay += by;
    float2 sv = h2[(size_t)node * 64 + lane];
    // di*(sum + di*self) = di*sum(dinv[s]h[s]) + di^2*h[node]
    float rx = di * fmaf(di, sv.x, ax);
    float ry = di * fmaf(di, sv.y, ay);
    float2 b = ((const float2*)bias)[lane];
    rx = fmaf(bscale, b.x, rx);
    ry = fmaf(bscale, b.y, ry);
    rx = fmaxf(rx, 0.f);                    // cells 0..2 only consumed via relu
    ry = fmaxf(ry, 0.f);
    if (addin) {
        float2 av = ((const float2*)addin)[(size_t)node * 64 + lane];
        rx += av.x; ry += av.y;
    }
    float2 o; o.x = rx; o.y = ry;
    ((float2*)outp)[(size_t)node * 64 + lane] = o;
}

// ---------------------------------------------------------------------------
// Fused prop(cell3) + log_softmax + head, over the M label rows only.
// cell3 is never materialized. One wave per label row.
// pred[m,c] = sum_d v_d Wh[d,c] - L*whsum[c] + bh[c], L = logsumexp(v)
// ---------------------------------------------------------------------------
__global__ __launch_bounds__(256)
void k_prop_final(const float* __restrict__ h, const int* __restrict__ row_ptr,
                  const int* __restrict__ col, const float* __restrict__ dinv,
                  const float* __restrict__ bias, float bscale,
                  const int* __restrict__ labels,
                  const float* __restrict__ Wh, const float* __restrict__ whs,
                  const float* __restrict__ bh, float* __restrict__ outp,
                  int m_total, int C) {
    __shared__ float vl[4][DIM];
    int wslot = threadIdx.x >> 6, lane = threadIdx.x & 63;
    int m = blockIdx.x * 4 + wslot;
    if (m >= m_total) return;
    int node = labels[m];
    int beg = row_ptr[node], end = row_ptr[node + 1];
    float di = dinv[node];
    const float2* h2 = (const float2*)h;
    float ax = 0.f, ay = 0.f, bx = 0.f, by = 0.f;
    int j = beg;
    for (; j + 4 <= end; j += 4) {
        int s0 = col[j], s1 = col[j + 1], s2 = col[j + 2], s3 = col[j + 3];
        float w0 = dinv[s0], w1 = dinv[s1], w2 = dinv[s2], w3 = dinv[s3];
        float2 v0 = h2[(size_t)s0 * 64 + lane];
        float2 v1 = h2[(size_t)s1 * 64 + lane];
        float2 v2 = h2[(size_t)s2 * 64 + lane];
        float2 v3 = h2[(size_t)s3 * 64 + lane];
        ax = fmaf(w0, v0.x, ax); ay = fmaf(w0, v0.y, ay);
        bx = fmaf(w1, v1.x, bx); by = fmaf(w1, v1.y, by);
        ax = fmaf(w2, v2.x, ax); ay = fmaf(w2, v2.y, ay);
        bx = fmaf(w3, v3.x, bx); by = fmaf(w3, v3.y, by);
    }
    for (; j < end; ++j) {
        int s = col[j];
        float w = dinv[s];
        float2 v = h2[(size_t)s * 64 + lane];
        ax = fmaf(w, v.x, ax); ay = fmaf(w, v.y, ay);
    }
    ax += bx; ay += by;
    float2 sv = h2[(size_t)node * 64 + lane];
    float vx = di * fmaf(di, sv.x, ax);
    float vy = di * fmaf(di, sv.y, ay);
    float2 b = ((const float2*)bias)[lane];
    vx = fmaf(bscale, b.x, vx);
    vy = fmaf(bscale, b.y, vy);
    // logsumexp over the 128 features of this row
    float mx = fmaxf(vx, vy);
    #pragma unroll
    for (int off = 32; off > 0; off >>= 1) mx = fmaxf(mx, __shfl_xor(mx, off, 64));
    float s = expf(vx - mx) + expf(vy - mx);
    #pragma unroll
    for (int off = 32; off > 0; off >>= 1) s += __shfl_xor(s, off, 64);
    float L = mx + logf(s);
    vl[wslot][2 * lane]     = vx;
    vl[wslot][2 * lane + 1] = vy;
    // same-wave LDS RAW: compiler inserts the required lgkmcnt wait
    if (lane < C) {
        float acc = 0.f;
        #pragma unroll 8
        for (int d = 0; d < DIM; ++d)
            acc = fmaf(vl[wslot][d], Wh[d * C + lane], acc);
        outp[(size_t)m * C + lane] = acc - L * whs[lane] + bh[lane];
    }
}

// column sums of Wh [128,40]
__global__ void k_whsum(const float* __restrict__ Wh, float* __restrict__ whs, int C) {
    int c = threadIdx.x;
    if (c < C) {
        float s = 0.f;
        for (int d = 0; d < DIM; ++d) s += Wh[d * C + c];
        whs[c] = s;
    }
}

// ---------------------------------------------------------------------------
extern "C" void kernel_launch(void* const* d_in, const int* in_sizes, int n_in,
                              void* d_out, int out_size, void* d_ws, size_t ws_size,
                              hipStream_t stream) {
    const float* x      = (const float*)d_in[0];
    const int*   edges  = (const int*)d_in[1];
    const int*   labels = (const int*)d_in[2];
    const float* W0 = (const float*)d_in[3];
    const float* b0 = (const float*)d_in[4];
    const float* W1 = (const float*)d_in[5];
    const float* b1 = (const float*)d_in[6];
    const float* W2 = (const float*)d_in[7];
    const float* b2 = (const float*)d_in[8];
    const float* W3 = (const float*)d_in[9];
    const float* b3 = (const float*)d_in[10];
    const float* Wh = (const float*)d_in[11];
    const float* bh = (const float*)d_in[12];
    float* out = (float*)d_out;

    const int N = in_sizes[0] / DIM;       // 50000
    const int E = in_sizes[1] / 2;         // 600000
    const int M = in_sizes[2];             // 25000
    const int C = in_sizes[12];            // 40

    // Workspace layout (256B-aligned slices)
    char* ws = (char*)d_ws;
    auto alloc = [&](size_t bytes) {
        char* p = ws;
        ws += (bytes + 255) & ~(size_t)255;
        return p;
    };
    float* dinv    = (float*)alloc((size_t)N * 4);
    int*   count   = (int*)  alloc((size_t)N * 4);
    int*   row_ptr = (int*)  alloc((size_t)(N + 1) * 4);
    int*   cursor  = (int*)  alloc((size_t)N * 4);
    int*   partial = (int*)  alloc((size_t)N * 4);
    int*   bsum    = (int*)  alloc(64 * 4);
    int*   col     = (int*)  alloc((size_t)E * 4);
    float* whs     = (float*)alloc(256);
    float* H  = (float*)alloc((size_t)N * DIM * 4);   // matmul output (all layers)
    float* R0 = (float*)alloc((size_t)N * DIM * 4);   // relu(cell0)
    float* A  = (float*)alloc((size_t)N * DIM * 4);   // running relu-sum

    const int* src = edges;
    const int* dst = edges + E;

    int egrid  = (E + 255) / 256;
    int sgrid  = (N + 1023) / 1024;        // scan blocks (49 for N=50000)
    int mmgrid = (N + 127) / 128;          // 128-row C-tiles
    int pgrid  = (N + 3) / 4;              // one wave per node, 4 waves/block

    // --- CSR build ---
    hipMemsetAsync(count, 0, (size_t)N * 4, stream);
    k_count<<<egrid, 256, 0, stream>>>(dst, count, E);
    k_scanA<<<sgrid, 1024, 0, stream>>>(count, partial, bsum, dinv, N);
    k_scanB<<<sgrid, 1024, 0, stream>>>(count, partial, bsum, row_ptr, cursor, N, sgrid);
    k_fill <<<egrid, 256, 0, stream>>>(src, dst, cursor, col, E);
    k_whsum<<<1, 64, 0, stream>>>(Wh, whs, C);

    // --- R0 = relu(cell0) = relu(Â(x W0) + b0) ---
    k_matmul<<<mmgrid, 256, 0, stream>>>(x, W0, H, N);
    k_prop  <<<pgrid, 256, 0, stream>>>(H, row_ptr, col, dinv, b0, 1.f, nullptr, R0, N);
    // --- A = R0 + relu(cell1),  cell1 = Â(R0 W1) + b1 ---
    k_matmul<<<mmgrid, 256, 0, stream>>>(R0, W1, H, N);
    k_prop  <<<pgrid, 256, 0, stream>>>(H, row_ptr, col, dinv, b1, 1.f, R0, A, N);
    // --- A += relu(cell2),  cell2 = Â(A W2) + 2 b2  (in-place row-local) ---
    k_matmul<<<mmgrid, 256, 0, stream>>>(A, W2, H, N);
    k_prop  <<<pgrid, 256, 0, stream>>>(H, row_ptr, col, dinv, b2, 2.f, A, A, N);
    // --- head over labels only: cell3 = Â(A W3) + 3 b3, never materialized ---
    k_matmul<<<mmgrid, 256, 0, stream>>>(A, W3, H, N);
    k_prop_final<<<(M + 3) / 4, 256, 0, stream>>>(H, row_ptr, col, dinv, b3, 3.f,
                                                  labels, Wh, whs, bh, out, M, C);
}

// Round 5
// 441.296 us; speedup vs baseline: 2.3631x; 1.1089x over previous
//
#include <hip/hip_runtime.h>
#include <hip/hip_bf16.h>
#include <cstdint>
#include <cstddef>

// Problem constants (from reference): N=50000, E=600000, D=128, C=40, M=25000
#define DIM 128
#define KT  64   // K-chunk for matmul LDS staging

__device__ __forceinline__ float bf2f(unsigned short u) {
    union { unsigned int i; float f; } c;
    c.i = ((unsigned int)u) << 16;
    return c.f;
}
__device__ __forceinline__ unsigned short f2bf(float f) {
    __hip_bfloat16 h = __float2bfloat16(f);   // RN-even
    return *(unsigned short*)&h;
}

// ---------------------------------------------------------------------------
// CSR build: count in-degrees, parallel scan (+dinv fused), fill column lists
// ---------------------------------------------------------------------------
__global__ void k_count(const int* __restrict__ dst, int* __restrict__ count, int e) {
    int i = blockIdx.x * 256 + threadIdx.x;
    if (i < e) atomicAdd(&count[dst[i]], 1);
}

// Parallel scan pass A: per-block (1024-elem) inclusive scan -> partial[],
// block totals -> bsum[]. dinv computed inline.
__global__ __launch_bounds__(1024)
void k_scanA(const int* __restrict__ count, int* __restrict__ partial,
             int* __restrict__ bsum, float* __restrict__ dinv, int n) {
    __shared__ int wsum[16];
    int tid = threadIdx.x, lane = tid & 63, wid = tid >> 6;
    int i = blockIdx.x * 1024 + tid;
    int v = (i < n) ? count[i] : 0;
    if (i < n) dinv[i] = rsqrtf(1.0f + (float)v);   // deg includes self-loop
    int x = v;
    #pragma unroll
    for (int off = 1; off < 64; off <<= 1) {
        int y = __shfl_up(x, off, 64);
        if (lane >= off) x += y;
    }
    if (lane == 63) wsum[wid] = x;
    __syncthreads();
    int waveoff = 0, total = 0;
    #pragma unroll
    for (int w = 0; w < 16; ++w) {
        int s = wsum[w];
        if (w < wid) waveoff += s;
        total += s;
    }
    if (i < n) partial[i] = x + waveoff;            // block-local inclusive
    if (tid == 0) bsum[blockIdx.x] = total;
}

// Pass B: block offset = wave-reduce of preceding block totals, emit
// row_ptr (inclusive, shifted) and cursor (exclusive).
__global__ __launch_bounds__(1024)
void k_scanB(const int* __restrict__ count, const int* __restrict__ partial,
             const int* __restrict__ bsum, int* __restrict__ row_ptr,
             int* __restrict__ cursor, int n, int nb) {
    __shared__ int s_off;
    int tid = threadIdx.x;
    if (tid < 64) {
        int carry = 0;
        for (int base = 0; base < nb; base += 64) {
            int idx = base + tid;
            int v = (idx < nb && idx < blockIdx.x) ? bsum[idx] : 0;
            #pragma unroll
            for (int off = 32; off > 0; off >>= 1) v += __shfl_xor(v, off, 64);
            carry += v;
        }
        if (tid == 0) s_off = carry;
    }
    __syncthreads();
    int off = s_off;
    int i = blockIdx.x * 1024 + tid;
    if (i < n) {
        int inc = partial[i] + off;
        row_ptr[i + 1] = inc;
        cursor[i] = inc - count[i];
    }
    if (blockIdx.x == 0 && tid == 0) row_ptr[0] = 0;
}

__global__ void k_fill(const int* __restrict__ src, const int* __restrict__ dst,
                       int* __restrict__ cursor, int* __restrict__ col, int e) {
    int i = blockIdx.x * 256 + threadIdx.x;
    if (i < e) {
        int d = dst[i];
        int pos = atomicAdd(&cursor[d], 1);
        col[pos] = src[i];
    }
}

// ---------------------------------------------------------------------------
// Matmul: H[N,128](bf16) = in[N,128](fp32) @ W[128,128](fp32).
// fp32 register-tiled (8x8/thread); output quantized to bf16 once per layer
// to halve the gather table (512B -> 256B per row).
// ---------------------------------------------------------------------------
__global__ __launch_bounds__(256)
void k_matmul(const float* __restrict__ in, const float* __restrict__ Wg,
              unsigned short* __restrict__ outp, int n) {
    __shared__ float At[KT][DIM];   // [k][row] 32KB
    __shared__ float Bs[KT][DIM];   // [k][col] 32KB
    int tid = threadIdx.x;
    int r0 = blockIdx.x * 128;
    int tx = tid & 15;              // col-group: cols tx*8 .. tx*8+7
    int ty = tid >> 4;              // row-group: rows ty*8 .. ty*8+7

    float acc[8][8];
    #pragma unroll
    for (int i = 0; i < 8; ++i)
        #pragma unroll
        for (int j = 0; j < 8; ++j) acc[i][j] = 0.f;

    for (int kc = 0; kc < DIM; kc += KT) {
        {   // stage A (128 rows x KT ks), transposed
            int row = tid >> 1;             // 0..127
            int kb  = (tid & 1) * 32;       // 0 or 32
            bool rowok = (r0 + row) < n;
            const float* gA = in + (size_t)(r0 + row) * DIM + kc + kb;
            #pragma unroll
            for (int j = 0; j < 8; ++j) {
                float4 v;
                if (rowok) v = *(const float4*)(gA + 4 * j);
                else { v.x = 0.f; v.y = 0.f; v.z = 0.f; v.w = 0.f; }
                int k = kb + 4 * j;
                At[k + 0][row] = v.x;       // 2-way bank alias across wave = free
                At[k + 1][row] = v.y;
                At[k + 2][row] = v.z;
                At[k + 3][row] = v.w;
            }
        }
        {   // stage B (KT ks x 128 cols), natural; coalesced float4
            int k  = tid >> 2;              // 0..63
            int cb = (tid & 3) * 32;
            const float* gB = Wg + (size_t)(kc + k) * DIM + cb;
            #pragma unroll
            for (int j = 0; j < 8; ++j)
                *(float4*)&Bs[k][cb + 4 * j] = *(const float4*)(gB + 4 * j);
        }
        __syncthreads();

        #pragma unroll 2
        for (int k = 0; k < KT; ++k) {
            float4 a0 = *(const float4*)&At[k][ty * 8];
            float4 a1 = *(const float4*)&At[k][ty * 8 + 4];
            float4 b0 = *(const float4*)&Bs[k][tx * 8];
            float4 b1 = *(const float4*)&Bs[k][tx * 8 + 4];
            float a[8] = {a0.x, a0.y, a0.z, a0.w, a1.x, a1.y, a1.z, a1.w};
            float b[8] = {b0.x, b0.y, b0.z, b0.w, b1.x, b1.y, b1.z, b1.w};
            #pragma unroll
            for (int i = 0; i < 8; ++i)
                #pragma unroll
                for (int j = 0; j < 8; ++j)
                    acc[i][j] = fmaf(a[i], b[j], acc[i][j]);
        }
        __syncthreads();
    }

    #pragma unroll
    for (int i = 0; i < 8; ++i) {
        int r = r0 + ty * 8 + i;
        if (r < n) {
            uint4 o;
            o.x = (unsigned)f2bf(acc[i][0]) | ((unsigned)f2bf(acc[i][1]) << 16);
            o.y = (unsigned)f2bf(acc[i][2]) | ((unsigned)f2bf(acc[i][3]) << 16);
            o.z = (unsigned)f2bf(acc[i][4]) | ((unsigned)f2bf(acc[i][5]) << 16);
            o.w = (unsigned)f2bf(acc[i][6]) | ((unsigned)f2bf(acc[i][7]) << 16);
            *(uint4*)(outp + (size_t)r * DIM + tx * 8) = o;   // 16B store
        }
    }
}

// ---------------------------------------------------------------------------
// Propagation over bf16 H, paired-edge half-wave gather.
// Lanes 0-31 handle edge j, lanes 32-63 edge j+1; each lane loads ushort4
// (4 bf16 features). Halves combined with __shfl_xor(32) at the end.
//   res = relu( di*sum dinv[s]*h[s] + di^2*h[node] + bscale*bias )
//   out[node] = (addin ? addin[node] : 0) + res      (fp32)
// ---------------------------------------------------------------------------
__global__ __launch_bounds__(256)
void k_prop(const unsigned short* __restrict__ h, const int* __restrict__ row_ptr,
            const int* __restrict__ col, const float* __restrict__ dinv,
            const float* __restrict__ bias, float bscale,
            const float* addin, float* outp, int n) {
    int node = (blockIdx.x * 256 + threadIdx.x) >> 6;
    int lane = threadIdx.x & 63;
    if (node >= n) return;
    int beg = row_ptr[node], end = row_ptr[node + 1];
    float di = dinv[node];
    int half = lane >> 5;          // which edge of the pair
    int fq   = lane & 31;          // feature quad: features 4*fq..4*fq+3
    const ushort4* h4 = (const ushort4*)h;   // one row = 32 ushort4
    float4 acc  = {0.f, 0.f, 0.f, 0.f};
    float4 acc2 = {0.f, 0.f, 0.f, 0.f};
    int j = beg;
    // 4 edges per iteration (2 per half-wave), 2 independent load chains
    for (; j + 4 <= end; j += 4) {
        int sA = col[j + half];
        int sB = col[j + 2 + half];
        float wA = dinv[sA], wB = dinv[sB];
        ushort4 vA = h4[(size_t)sA * 32 + fq];
        ushort4 vB = h4[(size_t)sB * 32 + fq];
        acc.x  = fmaf(wA, bf2f(vA.x), acc.x);
        acc.y  = fmaf(wA, bf2f(vA.y), acc.y);
        acc.z  = fmaf(wA, bf2f(vA.z), acc.z);
        acc.w  = fmaf(wA, bf2f(vA.w), acc.w);
        acc2.x = fmaf(wB, bf2f(vB.x), acc2.x);
        acc2.y = fmaf(wB, bf2f(vB.y), acc2.y);
        acc2.z = fmaf(wB, bf2f(vB.z), acc2.z);
        acc2.w = fmaf(wB, bf2f(vB.w), acc2.w);
    }
    // tail: 1..3 edges; odd half contributes weight 0 on a lone edge
    for (; j < end; j += 2) {
        bool act = (half == 0) || (end - j >= 2);
        int s = act ? col[j + half] : col[j];
        float w = act ? dinv[s] : 0.f;
        ushort4 v = h4[(size_t)s * 32 + fq];
        acc.x = fmaf(w, bf2f(v.x), acc.x);
        acc.y = fmaf(w, bf2f(v.y), acc.y);
        acc.z = fmaf(w, bf2f(v.z), acc.z);
        acc.w = fmaf(w, bf2f(v.w), acc.w);
    }
    acc.x += acc2.x; acc.y += acc2.y; acc.z += acc2.z; acc.w += acc2.w;
    // combine halves (both halves end with the full sum)
    acc.x += __shfl_xor(acc.x, 32, 64);
    acc.y += __shfl_xor(acc.y, 32, 64);
    acc.z += __shfl_xor(acc.z, 32, 64);
    acc.w += __shfl_xor(acc.w, 32, 64);
    // self-loop + bias + relu (+ addin), computed on all lanes, stored by half 0
    ushort4 sv = h4[(size_t)node * 32 + fq];
    float4 r;
    r.x = di * fmaf(di, bf2f(sv.x), acc.x);
    r.y = di * fmaf(di, bf2f(sv.y), acc.y);
    r.z = di * fmaf(di, bf2f(sv.z), acc.z);
    r.w = di * fmaf(di, bf2f(sv.w), acc.w);
    float4 b = ((const float4*)bias)[fq];
    r.x = fmaxf(fmaf(bscale, b.x, r.x), 0.f);
    r.y = fmaxf(fmaf(bscale, b.y, r.y), 0.f);
    r.z = fmaxf(fmaf(bscale, b.z, r.z), 0.f);
    r.w = fmaxf(fmaf(bscale, b.w, r.w), 0.f);
    if (half == 0) {
        if (addin) {
            float4 av = ((const float4*)addin)[(size_t)node * 32 + fq];
            r.x += av.x; r.y += av.y; r.z += av.z; r.w += av.w;
        }
        ((float4*)outp)[(size_t)node * 32 + fq] = r;   // 32 lanes x 16B = full row
    }
}

// ---------------------------------------------------------------------------
// Fused prop(cell3) + log_softmax + head over the M label rows only.
// Same paired-edge gather; Wh staged in LDS (kills 128 global loads/wave
// in the old epilogue -- that was ~25us of vmem issue).
// pred[m,c] = sum_d v_d Wh[d,c] - L*whsum[c] + bh[c], L = logsumexp(v)
// ---------------------------------------------------------------------------
__global__ __launch_bounds__(256)
void k_prop_final(const unsigned short* __restrict__ h, const int* __restrict__ row_ptr,
                  const int* __restrict__ col, const float* __restrict__ dinv,
                  const float* __restrict__ bias, float bscale,
                  const int* __restrict__ labels,
                  const float* __restrict__ Wh, const float* __restrict__ whs,
                  const float* __restrict__ bh, float* __restrict__ outp,
                  int m_total, int C) {
    __shared__ float WhS[DIM][40];   // 20KB; WhS[d][c], 2-way bank alias at read
    __shared__ float vl[4][DIM];
    // cooperative Wh staging BEFORE any early return (barrier divergence!)
    for (int idx = threadIdx.x; idx < DIM * C; idx += 256)
        WhS[idx / C][idx % C] = Wh[idx];
    __syncthreads();

    int wslot = threadIdx.x >> 6, lane = threadIdx.x & 63;
    int m = blockIdx.x * 4 + wslot;
    if (m >= m_total) return;
    int node = labels[m];
    int beg = row_ptr[node], end = row_ptr[node + 1];
    float di = dinv[node];
    int half = lane >> 5, fq = lane & 31;
    const ushort4* h4 = (const ushort4*)h;
    float4 acc  = {0.f, 0.f, 0.f, 0.f};
    float4 acc2 = {0.f, 0.f, 0.f, 0.f};
    int j = beg;
    for (; j + 4 <= end; j += 4) {
        int sA = col[j + half];
        int sB = col[j + 2 + half];
        float wA = dinv[sA], wB = dinv[sB];
        ushort4 vA = h4[(size_t)sA * 32 + fq];
        ushort4 vB = h4[(size_t)sB * 32 + fq];
        acc.x  = fmaf(wA, bf2f(vA.x), acc.x);
        acc.y  = fmaf(wA, bf2f(vA.y), acc.y);
        acc.z  = fmaf(wA, bf2f(vA.z), acc.z);
        acc.w  = fmaf(wA, bf2f(vA.w), acc.w);
        acc2.x = fmaf(wB, bf2f(vB.x), acc2.x);
        acc2.y = fmaf(wB, bf2f(vB.y), acc2.y);
        acc2.z = fmaf(wB, bf2f(vB.z), acc2.z);
        acc2.w = fmaf(wB, bf2f(vB.w), acc2.w);
    }
    for (; j < end; j += 2) {
        bool act = (half == 0) || (end - j >= 2);
        int s = act ? col[j + half] : col[j];
        float w = act ? dinv[s] : 0.f;
        ushort4 v = h4[(size_t)s * 32 + fq];
        acc.x = fmaf(w, bf2f(v.x), acc.x);
        acc.y = fmaf(w, bf2f(v.y), acc.y);
        acc.z = fmaf(w, bf2f(v.z), acc.z);
        acc.w = fmaf(w, bf2f(v.w), acc.w);
    }
    acc.x += acc2.x; acc.y += acc2.y; acc.z += acc2.z; acc.w += acc2.w;
    acc.x += __shfl_xor(acc.x, 32, 64);
    acc.y += __shfl_xor(acc.y, 32, 64);
    acc.z += __shfl_xor(acc.z, 32, 64);
    acc.w += __shfl_xor(acc.w, 32, 64);
    ushort4 sv = h4[(size_t)node * 32 + fq];
    float4 v;
    v.x = di * fmaf(di, bf2f(sv.x), acc.x);
    v.y = di * fmaf(di, bf2f(sv.y), acc.y);
    v.z = di * fmaf(di, bf2f(sv.z), acc.z);
    v.w = di * fmaf(di, bf2f(sv.w), acc.w);
    float4 b = ((const float4*)bias)[fq];
    v.x = fmaf(bscale, b.x, v.x);
    v.y = fmaf(bscale, b.y, v.y);
    v.z = fmaf(bscale, b.z, v.z);
    v.w = fmaf(bscale, b.w, v.w);
    // logsumexp over 128 features (halves are duplicates: 5-level butterfly)
    float mx = fmaxf(fmaxf(v.x, v.y), fmaxf(v.z, v.w));
    #pragma unroll
    for (int off = 16; off > 0; off >>= 1) mx = fmaxf(mx, __shfl_xor(mx, off, 64));
    float s = expf(v.x - mx) + expf(v.y - mx) + expf(v.z - mx) + expf(v.w - mx);
    #pragma unroll
    for (int off = 16; off > 0; off >>= 1) s += __shfl_xor(s, off, 64);
    float L = mx + logf(s);
    if (half == 0) *(float4*)&vl[wslot][4 * fq] = v;
    // same-wave LDS RAW: compiler inserts the required lgkmcnt wait
    if (lane < C) {
        float a = 0.f;
        #pragma unroll
        for (int dq = 0; dq < DIM / 4; ++dq) {
            float4 vv = *(const float4*)&vl[wslot][4 * dq];   // broadcast b128
            a = fmaf(vv.x, WhS[4 * dq + 0][lane], a);
            a = fmaf(vv.y, WhS[4 * dq + 1][lane], a);
            a = fmaf(vv.z, WhS[4 * dq + 2][lane], a);
            a = fmaf(vv.w, WhS[4 * dq + 3][lane], a);
        }
        outp[(size_t)m * C + lane] = a - L * whs[lane] + bh[lane];
    }
}

// column sums of Wh [128,40]
__global__ void k_whsum(const float* __restrict__ Wh, float* __restrict__ whs, int C) {
    int c = threadIdx.x;
    if (c < C) {
        float s = 0.f;
        for (int d = 0; d < DIM; ++d) s += Wh[d * C + c];
        whs[c] = s;
    }
}

// ---------------------------------------------------------------------------
extern "C" void kernel_launch(void* const* d_in, const int* in_sizes, int n_in,
                              void* d_out, int out_size, void* d_ws, size_t ws_size,
                              hipStream_t stream) {
    const float* x      = (const float*)d_in[0];
    const int*   edges  = (const int*)d_in[1];
    const int*   labels = (const int*)d_in[2];
    const float* W0 = (const float*)d_in[3];
    const float* b0 = (const float*)d_in[4];
    const float* W1 = (const float*)d_in[5];
    const float* b1 = (const float*)d_in[6];
    const float* W2 = (const float*)d_in[7];
    const float* b2 = (const float*)d_in[8];
    const float* W3 = (const float*)d_in[9];
    const float* b3 = (const float*)d_in[10];
    const float* Wh = (const float*)d_in[11];
    const float* bh = (const float*)d_in[12];
    float* out = (float*)d_out;

    const int N = in_sizes[0] / DIM;       // 50000
    const int E = in_sizes[1] / 2;         // 600000
    const int M = in_sizes[2];             // 25000
    const int C = in_sizes[12];            // 40

    // Workspace layout (256B-aligned slices)
    char* ws = (char*)d_ws;
    auto alloc = [&](size_t bytes) {
        char* p = ws;
        ws += (bytes + 255) & ~(size_t)255;
        return p;
    };
    float* dinv    = (float*)alloc((size_t)N * 4);
    int*   count   = (int*)  alloc((size_t)N * 4);
    int*   row_ptr = (int*)  alloc((size_t)(N + 1) * 4);
    int*   cursor  = (int*)  alloc((size_t)N * 4);
    int*   partial = (int*)  alloc((size_t)N * 4);
    int*   bsum    = (int*)  alloc(64 * 4);
    int*   col     = (int*)  alloc((size_t)E * 4);
    float* whs     = (float*)alloc(256);
    unsigned short* H = (unsigned short*)alloc((size_t)N * DIM * 2);  // bf16 table
    float* R0 = (float*)alloc((size_t)N * DIM * 4);   // relu(cell0)  fp32
    float* A  = (float*)alloc((size_t)N * DIM * 4);   // running relu-sum fp32

    const int* src = edges;
    const int* dst = edges + E;

    int egrid  = (E + 255) / 256;
    int sgrid  = (N + 1023) / 1024;        // scan blocks (49 for N=50000)
    int mmgrid = (N + 127) / 128;          // 128-row C-tiles
    int pgrid  = (N + 3) / 4;              // one wave per node, 4 waves/block

    // --- CSR build ---
    hipMemsetAsync(count, 0, (size_t)N * 4, stream);
    k_count<<<egrid, 256, 0, stream>>>(dst, count, E);
    k_scanA<<<sgrid, 1024, 0, stream>>>(count, partial, bsum, dinv, N);
    k_scanB<<<sgrid, 1024, 0, stream>>>(count, partial, bsum, row_ptr, cursor, N, sgrid);
    k_fill <<<egrid, 256, 0, stream>>>(src, dst, cursor, col, E);
    k_whsum<<<1, 64, 0, stream>>>(Wh, whs, C);

    // --- R0 = relu(cell0) = relu(Â(x W0) + b0) ---
    k_matmul<<<mmgrid, 256, 0, stream>>>(x, W0, H, N);
    k_prop  <<<pgrid, 256, 0, stream>>>(H, row_ptr, col, dinv, b0, 1.f, nullptr, R0, N);
    // --- A = R0 + relu(cell1),  cell1 = Â(R0 W1) + b1 ---
    k_matmul<<<mmgrid, 256, 0, stream>>>(R0, W1, H, N);
    k_prop  <<<pgrid, 256, 0, stream>>>(H, row_ptr, col, dinv, b1, 1.f, R0, A, N);
    // --- A += relu(cell2),  cell2 = Â(A W2) + 2 b2  (in-place row-local) ---
    k_matmul<<<mmgrid, 256, 0, stream>>>(A, W2, H, N);
    k_prop  <<<pgrid, 256, 0, stream>>>(H, row_ptr, col, dinv, b2, 2.f, A, A, N);
    // --- head over labels only: cell3 = Â(A W3) + 3 b3, never materialized ---
    k_matmul<<<mmgrid, 256, 0, stream>>>(A, W3, H, N);
    k_prop_final<<<(M + 3) / 4, 256, 0, stream>>>(H, row_ptr, col, dinv, b3, 3.f,
                                                  labels, Wh, whs, bh, out, M, C);
}